// Round 2
// baseline (109.797 us; speedup 1.0000x reference)
//
#include <hip/hip_runtime.h>
#include <math.h>

// Problem: DistanceLoss — y_pred (8,2,512,512) f32, y_true (8,2,512,512) f32 -> scalar f32.
// loss = mean over all elements of (1 + EDT(y_true)/511) * (softmax(y_pred,C) - y_true)^2
// EDT = exact 2D Euclidean distance transform per (n,c) image.

#define H 512
#define W 512
#define NIMG 16          // N*C = 8*2
#define HW (H * W)
#define TJ 32            // columns per pass-2 tile
#define RWIN 8           // pass-2 exact window radius; fallback handles the rest

// ---------------------------------------------------------------------------
// Pass 1: per-row 1D distance along width (min-plus scan), squared, row-major.
// f[j] = j + min_{k<=j}(g[k]-k) ; b[j] = -j + min_{k>=j}(g[k]+k) ; d1 = min(f,b)
// One wave (64 lanes) per row, 8 contiguous elements per lane.
// All values are exact small integers in fp32 -> bitwise matches reference scan.
// ---------------------------------------------------------------------------
__global__ __launch_bounds__(256) void edt_rows_kernel(const float* __restrict__ yt,
                                                       float* __restrict__ d1sq) {
    int wid = blockIdx.x * 4 + (threadIdx.x >> 6);
    int lane = threadIdx.x & 63;
    if (wid >= NIMG * H) return;
    int img = wid >> 9;          // /512
    int row = wid & (H - 1);

    const float* rp = yt + ((size_t)img * H + row) * W;
    int k0 = lane * 8;
    float4 va = *reinterpret_cast<const float4*>(rp + k0);
    float4 vb = *reinterpret_cast<const float4*>(rp + k0 + 4);
    float g[8] = { va.x, va.y, va.z, va.w, vb.x, vb.y, vb.z, vb.w };
    const float INF = 1024.0f;   // H + W, matches reference
    #pragma unroll
    for (int t = 0; t < 8; ++t) g[t] = (g[t] > 0.5f) ? 0.0f : INF;

    const float BIG = 3.0e38f;
    float pm[8], sm[8];

    // local prefix min of a[k] = g[k] - k
    float run = BIG;
    #pragma unroll
    for (int t = 0; t < 8; ++t) {
        float a = g[t] - (float)(k0 + t);
        run = fminf(run, a);
        pm[t] = run;
    }
    // inclusive wave min-scan (left to right)
    float incl = run;
    #pragma unroll
    for (int d = 1; d < 64; d <<= 1) {
        float o = __shfl_up(incl, d);
        if (lane >= d) incl = fminf(incl, o);
    }
    float excl = __shfl_up(incl, 1);
    if (lane == 0) excl = BIG;

    // local suffix min of c[k] = g[k] + k
    run = BIG;
    #pragma unroll
    for (int t = 7; t >= 0; --t) {
        float cc = g[t] + (float)(k0 + t);
        run = fminf(run, cc);
        sm[t] = run;
    }
    // inclusive wave min-scan (right to left)
    float incl2 = run;
    #pragma unroll
    for (int d = 1; d < 64; d <<= 1) {
        float o = __shfl_down(incl2, d);
        if (lane < 64 - d) incl2 = fminf(incl2, o);
    }
    float excl2 = __shfl_down(incl2, 1);
    if (lane == 63) excl2 = BIG;

    float out[8];
    #pragma unroll
    for (int t = 0; t < 8; ++t) {
        float kf = (float)(k0 + t);
        float f = kf + fminf(excl, pm[t]);
        float b = -kf + fminf(excl2, sm[t]);
        float d = fminf(f, b);
        out[t] = d * d;          // exact integer in fp32
    }
    float* op = d1sq + (size_t)img * HW + (size_t)row * W + k0;
    *reinterpret_cast<float4*>(op)     = make_float4(out[0], out[1], out[2], out[3]);
    *reinterpret_cast<float4*>(op + 4) = make_float4(out[4], out[5], out[6], out[7]);
}

// ---------------------------------------------------------------------------
// Pass 2: exact column envelope D2[i,j] = min_i' d1sq[i',j] + (i-i')^2,
// fused with softmax + squared error + weighted-mean reduction.
// Algebra: cand = i^2 + (-2i)*i' + (i'^2 + d1sq[i']); the i^2 is hoisted
// outside the min. All intermediates are exact integers < 2^24 in fp32.
//
// EXACT windowing: candidates with |i-i'| > RWIN are >= (RWIN+1)^2, so if the
// window min (including the +i^2 term) is <= (RWIN+1)^2 for every row, the
// window min IS the global min. Otherwise (never for dense random input, but
// required for exactness) scan the remaining rows.
//
// Block: 512 threads, one (image, 32-column tile); thread owns 1 column x 32 rows.
// ---------------------------------------------------------------------------
__global__ __launch_bounds__(512) void edt_cols_loss_kernel(const float* __restrict__ yp,
                                                            const float* __restrict__ yt,
                                                            const float* __restrict__ d1sq,
                                                            double* __restrict__ acc) {
    __shared__ float lw[H * TJ];     // 64 KB: d1sq tile, [i'][jl]
    __shared__ double wsum[8];

    int img = blockIdx.y;
    int j0 = blockIdx.x * TJ;
    int t = threadIdx.x;

    const float* dp = d1sq + (size_t)img * HW;
    for (int s = t; s < H * TJ; s += 512) {
        int i  = s >> 5;
        int jl = s & 31;
        lw[s] = dp[i * W + j0 + jl];
    }
    __syncthreads();

    int jl = t & 31;
    int ib = t >> 5;                 // 0..15
    int ibase = ib * 32;

    float am[32], mn[32];
    #pragma unroll
    for (int m = 0; m < 32; ++m) {
        am[m] = -2.0f * (float)(ibase + m);
        mn[m] = 3.0e38f;
    }

    const float* lwj = lw + jl;

    // --- exact windowed scan ---
    int lo = ibase - RWIN;          if (lo < 0) lo = 0;
    int hi = ibase + 31 + RWIN;     if (hi > H - 1) hi = H - 1;
    {
        float ipf  = (float)lo;
        float ipsq = ipf * ipf;      // exact (< 2^24)
        for (int ip = lo; ip <= hi; ++ip) {
            float w = lwj[ip * 32] + ipsq;
            #pragma unroll
            for (int m = 0; m < 32; ++m)
                mn[m] = fminf(mn[m], fmaf(am[m], ipf, w));
            ipsq += 2.0f * ipf + 1.0f;
            ipf  += 1.0f;
        }
    }
    // --- certify or fall back (exactness guard; dead for this input) ---
    bool need = false;
    const float thr = (float)((RWIN + 1) * (RWIN + 1));
    #pragma unroll
    for (int m = 0; m < 32; ++m) {
        float i_f = (float)(ibase + m);
        need |= (mn[m] + i_f * i_f > thr);
    }
    if (__any(need)) {
        float ipf  = 0.0f;
        float ipsq = 0.0f;
        for (int ip = 0; ip < lo; ++ip) {
            float w = lwj[ip * 32] + ipsq;
            #pragma unroll
            for (int m = 0; m < 32; ++m)
                mn[m] = fminf(mn[m], fmaf(am[m], ipf, w));
            ipsq += 2.0f * ipf + 1.0f;
            ipf  += 1.0f;
        }
        ipf  = (float)(hi + 1);
        ipsq = ipf * ipf;
        for (int ip = hi + 1; ip < H; ++ip) {
            float w = lwj[ip * 32] + ipsq;
            #pragma unroll
            for (int m = 0; m < 32; ++m)
                mn[m] = fminf(mn[m], fmaf(am[m], ipf, w));
            ipsq += 2.0f * ipf + 1.0f;
            ipf  += 1.0f;
        }
    }

    // Epilogue: loss contribution for this thread's 32 pixels.
    int n = img >> 1;
    int c = img & 1;
    const float* ypc = yp + (size_t)(n * 2 + c) * HW;
    const float* ypo = yp + (size_t)(n * 2 + (1 - c)) * HW;
    const float* ytc = yt + (size_t)img * HW;

    double local = 0.0;
    #pragma unroll
    for (int m = 0; m < 32; ++m) {
        int i = ibase + m;
        int idx = i * W + j0 + jl;
        float d2  = mn[m] + (float)(i * i);     // exact integer D^2
        float dmv = sqrtf(d2) / 511.0f;         // matches reference normalize
        float x0 = ypc[idx], x1 = ypo[idx];
        float mx = fmaxf(x0, x1);
        float e0 = expf(x0 - mx), e1 = expf(x1 - mx);
        float p  = e0 / (e0 + e1);
        float df = p - ytc[idx];
        local += (double)((1.0f + dmv) * (df * df));
    }

    // block reduce: wave shuffle then cross-wave via LDS
    #pragma unroll
    for (int d = 32; d > 0; d >>= 1) local += __shfl_down(local, d);
    int wv = t >> 6;
    if ((t & 63) == 0) wsum[wv] = local;
    __syncthreads();
    if (t == 0) {
        double s = 0.0;
        #pragma unroll
        for (int q = 0; q < 8; ++q) s += wsum[q];
        atomicAdd(acc, s);
    }
}

__global__ void finalize_kernel(const double* __restrict__ acc, float* __restrict__ out) {
    out[0] = (float)(acc[0] / (double)(8.0 * 2.0 * 512.0 * 512.0));
}

extern "C" void kernel_launch(void* const* d_in, const int* in_sizes, int n_in,
                              void* d_out, int out_size, void* d_ws, size_t ws_size,
                              hipStream_t stream) {
    const float* y_pred = (const float*)d_in[0];
    const float* y_true = (const float*)d_in[1];
    float* out = (float*)d_out;

    double* acc  = (double*)d_ws;
    float*  d1sq = (float*)((char*)d_ws + 256);

    hipMemsetAsync(d_ws, 0, sizeof(double), stream);

    edt_rows_kernel<<<dim3(NIMG * H / 4), 256, 0, stream>>>(y_true, d1sq);
    edt_cols_loss_kernel<<<dim3(W / TJ, NIMG), 512, 0, stream>>>(y_pred, y_true, d1sq, acc);
    finalize_kernel<<<1, 1, 0, stream>>>(acc, out);
}

// Round 3
// 100.129 us; speedup vs baseline: 1.0966x; 1.0966x over previous
//
#include <hip/hip_runtime.h>
#include <math.h>

// DistanceLoss — y_pred (8,2,512,512) f32, y_true (8,2,512,512) f32 -> scalar f32.
// loss = mean[(1 + EDT(y_true)/511) * (softmax(y_pred,C=2) - y_true)^2]
// EDT = exact 2D Euclidean distance transform per (n,c) image.

#define H 512
#define W 512
#define NIMG 16          // N*C = 8*2
#define HW (H * W)
#define TJ 32            // columns per pass-2 tile
#define RWIN 5           // pass-2 exact window radius; exact fallback guards the rest

// ---------------------------------------------------------------------------
// Pass 1: per-row 1D distance along width (min-plus scan), squared, row-major.
// f[j] = j + min_{k<=j}(g[k]-k) ; b[j] = -j + min_{k>=j}(g[k]+k) ; d1 = min(f,b)
// One wave (64 lanes) per row, 8 contiguous elements per lane.
// All values are exact small integers in fp32 -> bitwise matches reference scan.
// ---------------------------------------------------------------------------
__global__ __launch_bounds__(256) void edt_rows_kernel(const float* __restrict__ yt,
                                                       float* __restrict__ d1sq) {
    int wid = blockIdx.x * 4 + (threadIdx.x >> 6);
    int lane = threadIdx.x & 63;
    int img = wid >> 9;          // /512
    int row = wid & (H - 1);

    const float* rp = yt + ((size_t)img * H + row) * W;
    int k0 = lane * 8;
    float4 va = *reinterpret_cast<const float4*>(rp + k0);
    float4 vb = *reinterpret_cast<const float4*>(rp + k0 + 4);
    float g[8] = { va.x, va.y, va.z, va.w, vb.x, vb.y, vb.z, vb.w };
    const float INF = 1024.0f;   // H + W, matches reference
    #pragma unroll
    for (int t = 0; t < 8; ++t) g[t] = (g[t] > 0.5f) ? 0.0f : INF;

    const float BIG = 3.0e38f;
    float pm[8], sm[8];

    // local prefix min of a[k] = g[k] - k
    float run = BIG;
    #pragma unroll
    for (int t = 0; t < 8; ++t) {
        float a = g[t] - (float)(k0 + t);
        run = fminf(run, a);
        pm[t] = run;
    }
    // inclusive wave min-scan (left to right)
    float incl = run;
    #pragma unroll
    for (int d = 1; d < 64; d <<= 1) {
        float o = __shfl_up(incl, d);
        if (lane >= d) incl = fminf(incl, o);
    }
    float excl = __shfl_up(incl, 1);
    if (lane == 0) excl = BIG;

    // local suffix min of c[k] = g[k] + k
    run = BIG;
    #pragma unroll
    for (int t = 7; t >= 0; --t) {
        float cc = g[t] + (float)(k0 + t);
        run = fminf(run, cc);
        sm[t] = run;
    }
    // inclusive wave min-scan (right to left)
    float incl2 = run;
    #pragma unroll
    for (int d = 1; d < 64; d <<= 1) {
        float o = __shfl_down(incl2, d);
        if (lane < 64 - d) incl2 = fminf(incl2, o);
    }
    float excl2 = __shfl_down(incl2, 1);
    if (lane == 63) excl2 = BIG;

    float out[8];
    #pragma unroll
    for (int t = 0; t < 8; ++t) {
        float kf = (float)(k0 + t);
        float f = kf + fminf(excl, pm[t]);
        float b = -kf + fminf(excl2, sm[t]);
        float d = fminf(f, b);
        out[t] = d * d;          // exact integer in fp32
    }
    float* op = d1sq + (size_t)img * HW + (size_t)row * W + k0;
    *reinterpret_cast<float4*>(op)     = make_float4(out[0], out[1], out[2], out[3]);
    *reinterpret_cast<float4*>(op + 4) = make_float4(out[4], out[5], out[6], out[7]);
}

// ---------------------------------------------------------------------------
// Pass 2: exact column envelope D2[i,j] = min_i' d1sq[i',j] + (i-i')^2,
// fused with softmax + squared error + weighted-mean reduction.
// cand = i^2 + (-2i)*i' + (i'^2 + d1sq[i']); the i^2 hoisted outside the min.
// All intermediates are exact integers < 2^24 in fp32.
//
// EXACT windowing: candidates with |i-i'| > RWIN are >= (RWIN+1)^2; if the
// window min (with +i^2) is <= (RWIN+1)^2 for every row, it IS the global min.
// Otherwise (astronomically unlikely for dense random input, but required for
// exactness) scan the remaining rows.
//
// Block: 512 threads, one (image, 32-column tile); thread owns 1 col x 32 rows.
// Writes one double partial per block (no atomics, no zero-init needed).
// ---------------------------------------------------------------------------
__global__ __launch_bounds__(512) void edt_cols_loss_kernel(const float* __restrict__ yp,
                                                            const float* __restrict__ yt,
                                                            const float* __restrict__ d1sq,
                                                            double* __restrict__ part) {
    __shared__ float lw[H * TJ];     // 64 KB: d1sq tile, [i'][jl]
    __shared__ double wsum[8];

    int img = blockIdx.y;
    int j0 = blockIdx.x * TJ;
    int t = threadIdx.x;

    const float* dp = d1sq + (size_t)img * HW;
    for (int s = t; s < H * TJ; s += 512) {
        int i  = s >> 5;
        int jl = s & 31;
        lw[s] = dp[i * W + j0 + jl];
    }
    __syncthreads();

    int jl = t & 31;
    int ib = t >> 5;                 // 0..15
    int ibase = ib * 32;

    float am[32], mn[32];
    #pragma unroll
    for (int m = 0; m < 32; ++m) {
        am[m] = -2.0f * (float)(ibase + m);
        mn[m] = 3.0e38f;
    }

    const float* lwj = lw + jl;

    // --- exact windowed scan (paired candidates -> v_min3-friendly) ---
    int lo = ibase - RWIN;          if (lo < 0) lo = 0;
    int hi = ibase + 31 + RWIN;     if (hi > H - 1) hi = H - 1;
    int cnt = hi - lo + 1;
    {
        float ipf  = (float)lo;
        float ipsq = ipf * ipf;      // exact (< 2^24)
        int pairs = cnt >> 1;
        int ip = lo;
        for (int q = 0; q < pairs; ++q, ip += 2) {
            float w0    = lwj[ip * 32] + ipsq;
            float ipf1  = ipf + 1.0f;
            float ipsq1 = ipsq + 2.0f * ipf + 1.0f;
            float w1    = lwj[(ip + 1) * 32] + ipsq1;
            #pragma unroll
            for (int m = 0; m < 32; ++m) {
                float c0 = fmaf(am[m], ipf,  w0);
                float c1 = fmaf(am[m], ipf1, w1);
                mn[m] = fminf(fminf(mn[m], c0), c1);   // v_min3_f32 bait
            }
            ipf  = ipf1 + 1.0f;
            ipsq = ipsq1 + 2.0f * ipf1 + 1.0f;
        }
        if (cnt & 1) {
            float w = lwj[hi * 32] + ipsq;
            #pragma unroll
            for (int m = 0; m < 32; ++m)
                mn[m] = fminf(mn[m], fmaf(am[m], ipf, w));
        }
    }
    // --- certify or fall back (exactness guard; dead for this input) ---
    bool need = false;
    const float thr = (float)((RWIN + 1) * (RWIN + 1));
    #pragma unroll
    for (int m = 0; m < 32; ++m) {
        float i_f = (float)(ibase + m);
        need |= (mn[m] + i_f * i_f > thr);
    }
    if (__any(need)) {
        float ipf  = 0.0f;
        float ipsq = 0.0f;
        for (int ip = 0; ip < lo; ++ip) {
            float w = lwj[ip * 32] + ipsq;
            #pragma unroll
            for (int m = 0; m < 32; ++m)
                mn[m] = fminf(mn[m], fmaf(am[m], ipf, w));
            ipsq += 2.0f * ipf + 1.0f;
            ipf  += 1.0f;
        }
        ipf  = (float)(hi + 1);
        ipsq = ipf * ipf;
        for (int ip = hi + 1; ip < H; ++ip) {
            float w = lwj[ip * 32] + ipsq;
            #pragma unroll
            for (int m = 0; m < 32; ++m)
                mn[m] = fminf(mn[m], fmaf(am[m], ipf, w));
            ipsq += 2.0f * ipf + 1.0f;
            ipf  += 1.0f;
        }
    }

    // Epilogue: loss contribution for this thread's 32 pixels.
    int n = img >> 1;
    int c = img & 1;
    const float* ypc = yp + (size_t)(n * 2 + c) * HW;
    const float* ypo = yp + (size_t)(n * 2 + (1 - c)) * HW;
    const float* ytc = yt + (size_t)img * HW;

    double local = 0.0;
    #pragma unroll
    for (int m = 0; m < 32; ++m) {
        int i = ibase + m;
        int idx = i * W + j0 + jl;
        float d2  = mn[m] + (float)(i * i);     // exact integer D^2
        float dmv = sqrtf(d2) / 511.0f;         // matches reference normalize
        float x0 = ypc[idx], x1 = ypo[idx];
        float mx = fmaxf(x0, x1);
        float e0 = expf(x0 - mx), e1 = expf(x1 - mx);
        float p  = e0 / (e0 + e1);
        float df = p - ytc[idx];
        local += (double)((1.0f + dmv) * (df * df));
    }

    // block reduce: wave shuffle then cross-wave via LDS
    #pragma unroll
    for (int d = 32; d > 0; d >>= 1) local += __shfl_down(local, d);
    int wv = t >> 6;
    if ((t & 63) == 0) wsum[wv] = local;
    __syncthreads();
    if (t == 0) {
        double s = 0.0;
        #pragma unroll
        for (int q = 0; q < 8; ++q) s += wsum[q];
        part[blockIdx.y * gridDim.x + blockIdx.x] = s;
    }
}

// Sum the 256 per-block partials and normalize.
__global__ __launch_bounds__(256) void finalize_kernel(const double* __restrict__ part,
                                                       float* __restrict__ out) {
    __shared__ double ws[4];
    int t = threadIdx.x;
    double v = part[t];
    #pragma unroll
    for (int d = 32; d > 0; d >>= 1) v += __shfl_down(v, d);
    if ((t & 63) == 0) ws[t >> 6] = v;
    __syncthreads();
    if (t == 0)
        out[0] = (float)((ws[0] + ws[1] + ws[2] + ws[3]) / (double)(NIMG * HW));
}

extern "C" void kernel_launch(void* const* d_in, const int* in_sizes, int n_in,
                              void* d_out, int out_size, void* d_ws, size_t ws_size,
                              hipStream_t stream) {
    const float* y_pred = (const float*)d_in[0];
    const float* y_true = (const float*)d_in[1];
    float* out = (float*)d_out;

    double* part = (double*)d_ws;                       // 256 doubles
    float*  d1sq = (float*)((char*)d_ws + 8192);        // 16.8 MB

    edt_rows_kernel<<<dim3(NIMG * H / 4), 256, 0, stream>>>(y_true, d1sq);
    edt_cols_loss_kernel<<<dim3(W / TJ, NIMG), 512, 0, stream>>>(y_pred, y_true, d1sq, part);
    finalize_kernel<<<1, 256, 0, stream>>>(part, out);
}

// Round 6
// 91.364 us; speedup vs baseline: 1.2018x; 1.0959x over previous
//
#include <hip/hip_runtime.h>
#include <math.h>

// DistanceLoss — y_pred (8,2,512,512) f32, y_true (8,2,512,512) f32 -> scalar f32.
// loss = mean[(1 + EDT(y_true)/511) * (softmax(y_pred,C=2) - y_true)^2]
// EDT = exact 2D Euclidean distance transform per (n,c) image.

#define H 512
#define W 512
#define NIMG 16          // N*C = 8*2
#define HW (H * W)
#define RW 5             // exact window radius for the column pass
#define SEG 16           // rows per thread in pass 2
#define WLEN (SEG + 2 * RW)   // 26 halo rows per thread

// ---------------------------------------------------------------------------
// Pass 1: per-row 1D distance along width (min-plus scan), squared, row-major.
// f[j] = j + min_{k<=j}(g[k]-k) ; b[j] = -j + min_{k>=j}(g[k]+k) ; d1 = min(f,b)
// One wave (64 lanes) per row, 8 contiguous elements per lane.
// All values exact small integers in fp32 -> matches reference scan exactly.
// ---------------------------------------------------------------------------
__global__ __launch_bounds__(256) void edt_rows_kernel(const float* __restrict__ yt,
                                                       float* __restrict__ d1sq) {
    int wid = blockIdx.x * 4 + (threadIdx.x >> 6);
    int lane = threadIdx.x & 63;
    int img = wid >> 9;          // /512
    int row = wid & (H - 1);

    const float* rp = yt + ((size_t)img * H + row) * W;
    int k0 = lane * 8;
    float4 va = *reinterpret_cast<const float4*>(rp + k0);
    float4 vb = *reinterpret_cast<const float4*>(rp + k0 + 4);
    float g[8] = { va.x, va.y, va.z, va.w, vb.x, vb.y, vb.z, vb.w };
    const float INF = 1024.0f;   // H + W, matches reference
    #pragma unroll
    for (int t = 0; t < 8; ++t) g[t] = (g[t] > 0.5f) ? 0.0f : INF;

    const float BIG = 3.0e38f;
    float pm[8], sm[8];

    float run = BIG;
    #pragma unroll
    for (int t = 0; t < 8; ++t) {
        float a = g[t] - (float)(k0 + t);
        run = fminf(run, a);
        pm[t] = run;
    }
    float incl = run;
    #pragma unroll
    for (int d = 1; d < 64; d <<= 1) {
        float o = __shfl_up(incl, d);
        if (lane >= d) incl = fminf(incl, o);
    }
    float excl = __shfl_up(incl, 1);
    if (lane == 0) excl = BIG;

    run = BIG;
    #pragma unroll
    for (int t = 7; t >= 0; --t) {
        float cc = g[t] + (float)(k0 + t);
        run = fminf(run, cc);
        sm[t] = run;
    }
    float incl2 = run;
    #pragma unroll
    for (int d = 1; d < 64; d <<= 1) {
        float o = __shfl_down(incl2, d);
        if (lane < 64 - d) incl2 = fminf(incl2, o);
    }
    float excl2 = __shfl_down(incl2, 1);
    if (lane == 63) excl2 = BIG;

    float out[8];
    #pragma unroll
    for (int t = 0; t < 8; ++t) {
        float kf = (float)(k0 + t);
        float f = kf + fminf(excl, pm[t]);
        float b = -kf + fminf(excl2, sm[t]);
        float d = fminf(f, b);
        out[t] = d * d;          // exact integer in fp32
    }
    float* op = d1sq + (size_t)img * HW + (size_t)row * W + k0;
    *reinterpret_cast<float4*>(op)     = make_float4(out[0], out[1], out[2], out[3]);
    *reinterpret_cast<float4*>(op + 4) = make_float4(out[4], out[5], out[6], out[7]);
}

// ---------------------------------------------------------------------------
// Pass 2 (LDS-free, register-windowed): per thread, one column x SEG rows.
// D2[i,j] = min_k (d1sq[i-RW+k, j] + C2[k]),  C2[k] = (RW-k)^2 — constants!
// 26 fully-coalesced independent global loads per thread (deep MLP), then
// 16x21 add/min in registers. Exactness: if any window min > (RW+1)^2 the
// window might not contain the true argmin -> full-column fallback scan
// (astronomically improbable for dense random input, but exact).
// Fused epilogue: softmax + squared error + (1+EDT/511) weight + reduction.
// Grid: (2 j-halves, 32 i-tiles, 16 images) = 1024 blocks x 256 threads.
// ---------------------------------------------------------------------------
__global__ __launch_bounds__(256) void edt_cols_loss_kernel(const float* __restrict__ yp,
                                                            const float* __restrict__ yt,
                                                            const float* __restrict__ d1sq,
                                                            double* __restrict__ part) {
    __shared__ double wsum[4];

    int jl  = threadIdx.x;                 // 0..255
    int j   = blockIdx.x * 256 + jl;       // column
    int i0  = blockIdx.y * SEG;            // first output row
    int img = blockIdx.z;

    const float* dp = d1sq + (size_t)img * HW;
    const float BIG = 3.0e38f;

    float wsq[WLEN];
    #pragma unroll
    for (int k = 0; k < WLEN; ++k) {
        int ip = i0 - RW + k;
        if (ip >= 0 && ip < H) wsq[k] = dp[ip * W + j];   // uniform branch per k
        else                   wsq[k] = BIG;
    }

    const float C2[2 * RW + 1] = {25.f,16.f,9.f,4.f,1.f,0.f,1.f,4.f,9.f,16.f,25.f};
    float mn[SEG];
    #pragma unroll
    for (int m = 0; m < SEG; ++m) {
        float v = wsq[m] + C2[0];
        #pragma unroll
        for (int k = 1; k < 2 * RW + 1; ++k)
            v = fminf(v, wsq[m + k] + C2[k]);
        mn[m] = v;
    }

    // certification + exact fallback (dead for this input)
    bool need = false;
    const float thr = (float)((RW + 1) * (RW + 1));
    #pragma unroll
    for (int m = 0; m < SEG; ++m) need |= (mn[m] > thr);
    if (__any(need)) {
        for (int ip = 0; ip < H; ++ip) {
            float w = dp[ip * W + j];
            #pragma unroll
            for (int m = 0; m < SEG; ++m) {
                int d = (i0 + m) - ip;
                mn[m] = fminf(mn[m], w + (float)(d * d));
            }
        }
    }

    // Epilogue: loss contribution for this thread's SEG pixels.
    int n = img >> 1;
    int c = img & 1;
    const float* ypc = yp + (size_t)(n * 2 + c) * HW;
    const float* ypo = yp + (size_t)(n * 2 + (1 - c)) * HW;
    const float* ytc = yt + (size_t)img * HW;

    double local = 0.0;
    #pragma unroll
    for (int m = 0; m < SEG; ++m) {
        int i = i0 + m;
        int idx = i * W + j;
        float dmv = sqrtf(mn[m]) / 511.0f;      // exact integer D^2 -> normalized EDT
        float x0 = ypc[idx], x1 = ypo[idx];
        float mx = fmaxf(x0, x1);
        float e0 = expf(x0 - mx), e1 = expf(x1 - mx);
        float p  = e0 / (e0 + e1);
        float df = p - ytc[idx];
        local += (double)((1.0f + dmv) * (df * df));
    }

    // block reduce: wave shuffle then cross-wave via LDS
    #pragma unroll
    for (int d = 32; d > 0; d >>= 1) local += __shfl_down(local, d);
    int wv = threadIdx.x >> 6;
    if ((threadIdx.x & 63) == 0) wsum[wv] = local;
    __syncthreads();
    if (threadIdx.x == 0) {
        double s = wsum[0] + wsum[1] + wsum[2] + wsum[3];
        part[((blockIdx.z * gridDim.y) + blockIdx.y) * gridDim.x + blockIdx.x] = s;
    }
}

// Sum the 1024 per-block partials and normalize.
__global__ __launch_bounds__(256) void finalize_kernel(const double* __restrict__ part,
                                                       float* __restrict__ out) {
    __shared__ double ws[4];
    int t = threadIdx.x;
    double v = part[t] + part[t + 256] + part[t + 512] + part[t + 768];
    #pragma unroll
    for (int d = 32; d > 0; d >>= 1) v += __shfl_down(v, d);
    if ((t & 63) == 0) ws[t >> 6] = v;
    __syncthreads();
    if (t == 0)
        out[0] = (float)((ws[0] + ws[1] + ws[2] + ws[3]) / (double)(NIMG * HW));
}

extern "C" void kernel_launch(void* const* d_in, const int* in_sizes, int n_in,
                              void* d_out, int out_size, void* d_ws, size_t ws_size,
                              hipStream_t stream) {
    const float* y_pred = (const float*)d_in[0];
    const float* y_true = (const float*)d_in[1];
    float* out = (float*)d_out;

    double* part = (double*)d_ws;                       // 1024 doubles
    float*  d1sq = (float*)((char*)d_ws + 16384);       // 16.8 MB

    edt_rows_kernel<<<dim3(NIMG * H / 4), 256, 0, stream>>>(y_true, d1sq);
    edt_cols_loss_kernel<<<dim3(2, H / SEG, NIMG), 256, 0, stream>>>(y_pred, y_true, d1sq, part);
    finalize_kernel<<<1, 256, 0, stream>>>(part, out);
}